// Round 16
// baseline (37.233 us; speedup 1.0000x reference)
//
#include <hip/hip_runtime.h>
#include <math.h>

// Problem constants
constexpr int Bn = 512;
constexpr int Tn = 512;
constexpr int Dn = 128;
constexpr int Hn = 128;
constexpr int NT = 512;       // threads per block (one block per batch)
constexpr int NW = NT / 64;   // 8 waves

typedef float f4 __attribute__((ext_vector_type(4)));

// Sum across a 16-lane row group via DPP row rotations (pure VALU).
__device__ __forceinline__ float rowsum16(float x) {
    int v;
    v = __float_as_int(x);
    x += __int_as_float(__builtin_amdgcn_update_dpp(0, v, 0x121, 0xF, 0xF, true)); // row_ror:1
    v = __float_as_int(x);
    x += __int_as_float(__builtin_amdgcn_update_dpp(0, v, 0x122, 0xF, 0xF, true)); // row_ror:2
    v = __float_as_int(x);
    x += __int_as_float(__builtin_amdgcn_update_dpp(0, v, 0x124, 0xF, 0xF, true)); // row_ror:4
    v = __float_as_int(x);
    x += __int_as_float(__builtin_amdgcn_update_dpp(0, v, 0x128, 0xF, 0xF, true)); // row_ror:8
    return x;
}
// Full 32-lane sum: rowsum16 then exchange across the xor-16 pair (BitMode swizzle).
__device__ __forceinline__ float rowsum32(float x) {
    x = rowsum16(x);
    x += __int_as_float(__builtin_amdgcn_ds_swizzle(__float_as_int(x), 0x401F)); // xor 16
    return x;
}

__global__ __launch_bounds__(NT, 6)   // 6 waves/EU -> 3 blocks/CU (24 waves/CU), VGPR cap 85
void single_attn_fused5(const float* __restrict__ input,   // [B,T,D]
                        const int*   __restrict__ mask,    // [B,T]
                        const float* __restrict__ Wt,      // [D,H]
                        const float* __restrict__ Wx,      // [D,H]
                        const float* __restrict__ rate,    // [1]
                        float* __restrict__ out_v,         // [B,D]
                        float* __restrict__ out_a)         // [B,T]
{
    const int b    = blockIdx.x;
    const int tid  = threadIdx.x;
    const int lane = tid & 63;
    const int wid  = tid >> 6;
    const int c32  = lane & 31;    // f4 column 0..31 (32 lanes cover one row of 128 floats)
    const int rh   = lane >> 5;    // row half 0/1 within wave
    const float* __restrict__ inb = input + (size_t)b * Tn * Dn;
    const f4* __restrict__ in4 = (const f4*)inb;

    __shared__ float ps[Tn];          // 2 KB unnormalized weights
    __shared__ int   msk[Tn];         // 2 KB
    __shared__ float lv[Dn];
    __shared__ float qs[Hn];
    __shared__ float us[Dn];
    __shared__ float redl[NW];
    __shared__ int   ired[NW];
    __shared__ float vp[16 * 132];    // 8.4 KB v partials (16 groups x 128 floats, stride 132)

    // ---- prologue: last_idx, lv, q = lv@Wt, u = Wx@q ----
    const int mv = mask[(size_t)b * Tn + tid];
    msk[tid] = mv;
    {
        int ms = mv;
        #pragma unroll
        for (int off = 32; off > 0; off >>= 1) ms += __shfl_down(ms, off, 64);
        if (lane == 0) ired[wid] = ms;
    }
    __syncthreads();
    int last_idx;
    {
        int s = 0;
        #pragma unroll
        for (int w = 0; w < NW; ++w) s += ired[w];
        last_idx = s - 1;
    }
    if (tid < Dn) lv[tid] = inb[(size_t)last_idx * Dn + tid];
    __syncthreads();
    if (tid < Hn) {
        float a0 = 0.f, a1 = 0.f;
        #pragma unroll 16
        for (int d0 = 0; d0 < Dn; d0 += 2) {
            a0 = fmaf(lv[d0],     Wt[d0 * Hn + tid],       a0);
            a1 = fmaf(lv[d0 + 1], Wt[(d0 + 1) * Hn + tid], a1);
        }
        qs[tid] = a0 + a1;
    }
    __syncthreads();
    if (tid < Dn) {
        float a0 = 0.f, a1 = 0.f;
        const float* wxr = Wx + tid * Hn;
        #pragma unroll 16
        for (int h = 0; h < Hn; h += 2) {
            a0 = fmaf(wxr[h],     qs[h],     a0);
            a1 = fmaf(wxr[h + 1], qs[h + 1], a1);
        }
        us[tid] = a0 + a1;
    }
    __syncthreads();

    const float srate = 1.f / (1.f + __expf(-rate[0]));
    const f4 u4 = ((const f4*)us)[c32];

    // ---- fused streaming pass: dot -> p -> weighted accumulate, input read ONCE ----
    // 32 lanes per row, 1 f4/lane/iter: halves in-flight VGPRs vs 16-lane layout,
    // making the 85-VGPR cap (3 blocks/CU) feasible without spills.
    // e = relu(sig/den) in [0, ~1.45] (den >= sigmoid(0.8)*log(2.72) ~= 0.69),
    // so exp(e) <= 4.3: softmax needs no max subtraction.
    f4 vacc = (f4)(0.f);
    float lsum = 0.f;

    #pragma unroll 8
    for (int it = 0; it < 32; ++it) {
        const int row = it * 16 + wid * 2 + rh;    // == t  (16 rows per block-iter)
        const f4 x = in4[row * 32 + c32];
        float dot = x.x * u4.x + x.y * u4.y;
        dot = fmaf(x.z, u4.z, dot);
        dot = fmaf(x.w, u4.w, dot);
        dot = rowsum32(dot);
        const float sig = 1.f / (1.f + __expf(-dot));
        const float den = srate * (__logf(2.72f + (1.f - sig)) * (float)(Tn - row));
        const float e   = fmaxf(sig / den, 0.f);
        const float p   = msk[row] ? __expf(e) : 0.f;
        vacc += p * x;
        if (c32 == 0) { ps[row] = p; lsum += p; }
    }

    // stash v partials: group = wid*2 + rh (16 groups), 16B-aligned (132*4 % 16 == 16B ok: c32*16)
    {
        float* vr = vp + (wid * 2 + rh) * 132 + c32 * 4;
        *((f4*)vr) = vacc;
    }
    // block-reduce l (nonzero on lanes 0 and 32 of each wave)
    float ls = lsum;
    #pragma unroll
    for (int off = 32; off > 0; off >>= 1) ls += __shfl_down(ls, off, 64);
    if (lane == 0) redl[wid] = ls;
    __syncthreads();   // vp + ps + redl visible

    float l = 0.f;
    #pragma unroll
    for (int w = 0; w < NW; ++w) l += redl[w];
    const float inv_l = 1.f / l;

    out_a[(size_t)b * Tn + tid] = ps[tid] * inv_l;

    if (tid < Dn) {
        float s = 0.f;
        #pragma unroll
        for (int r = 0; r < 16; ++r) s += vp[r * 132 + tid];
        out_v[(size_t)b * Dn + tid] = s * inv_l;
    }
}

extern "C" void kernel_launch(void* const* d_in, const int* in_sizes, int n_in,
                              void* d_out, int out_size, void* d_ws, size_t ws_size,
                              hipStream_t stream) {
    const float* input = (const float*)d_in[0];   // [B,T,D]
    const int*   mask  = (const int*)d_in[1];     // [B,T]
    const float* Wt    = (const float*)d_in[2];   // [D,H]
    const float* Wx    = (const float*)d_in[3];   // [D,H]
    const float* rate  = (const float*)d_in[4];   // [1]

    float* out   = (float*)d_out;
    float* out_v = out;                 // [B,D]  (return order: v, a)
    float* out_a = out + Bn * Dn;       // [B,T]

    single_attn_fused5<<<Bn, NT, 0, stream>>>(input, mask, Wt, Wx, rate, out_v, out_a);
}

// Round 17
// 32.429 us; speedup vs baseline: 1.1481x; 1.1481x over previous
//
#include <hip/hip_runtime.h>
#include <math.h>

// Problem constants
constexpr int Bn = 512;
constexpr int Tn = 512;
constexpr int Dn = 128;
constexpr int Hn = 128;
constexpr int NT = 512;       // threads per block (one block per batch)
constexpr int NW = NT / 64;   // 8 waves

// Sum across the 16-lane row group via DPP row rotations (pure VALU, no LDS).
// After ror:1,2,4,8 accumulation every lane in the 16-group holds the full sum.
__device__ __forceinline__ float rowsum16(float x) {
    int v;
    v = __float_as_int(x);
    x += __int_as_float(__builtin_amdgcn_update_dpp(0, v, 0x121, 0xF, 0xF, true)); // row_ror:1
    v = __float_as_int(x);
    x += __int_as_float(__builtin_amdgcn_update_dpp(0, v, 0x122, 0xF, 0xF, true)); // row_ror:2
    v = __float_as_int(x);
    x += __int_as_float(__builtin_amdgcn_update_dpp(0, v, 0x124, 0xF, 0xF, true)); // row_ror:4
    v = __float_as_int(x);
    x += __int_as_float(__builtin_amdgcn_update_dpp(0, v, 0x128, 0xF, 0xF, true)); // row_ror:8
    return x;
}

__global__ __launch_bounds__(NT, 4)   // VGPR<=128 -> 2 blocks/CU (16 waves/CU); proven spill-free
void single_attn_fused3(const float* __restrict__ input,   // [B,T,D]
                        const int*   __restrict__ mask,    // [B,T]
                        const float* __restrict__ Wt,      // [D,H]
                        const float* __restrict__ Wx,      // [D,H]
                        const float* __restrict__ rate,    // [1]
                        float* __restrict__ out_v,         // [B,D]
                        float* __restrict__ out_a)         // [B,T]
{
    const int b    = blockIdx.x;
    const int tid  = threadIdx.x;
    const int lane = tid & 63;
    const int wid  = tid >> 6;
    const int seg  = tid & 15;     // 16 lanes per row; floats seg*8..seg*8+7
    const int rg   = tid >> 4;     // row group 0..31
    const float* __restrict__ inb = input + (size_t)b * Tn * Dn;
    const float4* __restrict__ in4 = (const float4*)inb;

    __shared__ float ps[Tn];          // 2 KB unnormalized weights
    __shared__ int   msk[Tn];         // 2 KB
    __shared__ float lv[Dn];
    __shared__ float qs[Hn];
    __shared__ float us[Dn];
    __shared__ float redl[NW];
    __shared__ int   ired[NW];
    __shared__ float vp[32 * 132];    // 16.9 KB v partials

    // ---- prologue: last_idx, lv, q = lv@Wt, u = Wx@q ----
    const int mv = mask[(size_t)b * Tn + tid];
    msk[tid] = mv;
    {
        int ms = mv;
        #pragma unroll
        for (int off = 32; off > 0; off >>= 1) ms += __shfl_down(ms, off, 64);
        if (lane == 0) ired[wid] = ms;
    }
    __syncthreads();
    int last_idx;
    {
        int s = 0;
        #pragma unroll
        for (int w = 0; w < NW; ++w) s += ired[w];
        last_idx = s - 1;
    }
    if (tid < Dn) lv[tid] = inb[(size_t)last_idx * Dn + tid];
    __syncthreads();
    if (tid < Hn) {
        float a0 = 0.f, a1 = 0.f;
        #pragma unroll 16
        for (int d0 = 0; d0 < Dn; d0 += 2) {
            a0 = fmaf(lv[d0],     Wt[d0 * Hn + tid],       a0);
            a1 = fmaf(lv[d0 + 1], Wt[(d0 + 1) * Hn + tid], a1);
        }
        qs[tid] = a0 + a1;
    }
    __syncthreads();
    if (tid < Dn) {
        float a0 = 0.f, a1 = 0.f;
        const float* wxr = Wx + tid * Hn;
        #pragma unroll 16
        for (int h = 0; h < Hn; h += 2) {
            a0 = fmaf(wxr[h],     qs[h],     a0);
            a1 = fmaf(wxr[h + 1], qs[h + 1], a1);
        }
        us[tid] = a0 + a1;
    }
    __syncthreads();

    const float srate = 1.f / (1.f + __expf(-rate[0]));
    const float4 u4a = ((const float4*)us)[seg * 2];
    const float4 u4b = ((const float4*)us)[seg * 2 + 1];

    // ---- fused streaming pass: dot -> p -> weighted accumulate, input read ONCE ----
    // e = relu(sig/den) in [0, ~1.45] (den >= sigmoid(0.8)*log(2.72) ~= 0.69),
    // so exp(e) <= 4.3: softmax needs no max subtraction.
    float4 v0 = make_float4(0.f, 0.f, 0.f, 0.f);
    float4 v1 = make_float4(0.f, 0.f, 0.f, 0.f);
    float  lsum = 0.f;

    #pragma unroll 8
    for (int it = 0; it < 16; ++it) {
        const int row = it * 32 + rg;              // == t
        const float4 x0 = in4[row * 32 + seg * 2];
        const float4 x1 = in4[row * 32 + seg * 2 + 1];
        float dot = x0.x * u4a.x + x0.y * u4a.y + x0.z * u4a.z + x0.w * u4a.w;
        dot = fmaf(x1.x, u4b.x, dot);
        dot = fmaf(x1.y, u4b.y, dot);
        dot = fmaf(x1.z, u4b.z, dot);
        dot = fmaf(x1.w, u4b.w, dot);
        dot = rowsum16(dot);                       // DPP reduce: no DS ops
        const float sig = 1.f / (1.f + __expf(-dot));
        const float den = srate * (__logf(2.72f + (1.f - sig)) * (float)(Tn - row));
        const float e   = fmaxf(sig / den, 0.f);
        const float p   = msk[row] ? __expf(e) : 0.f;
        v0.x = fmaf(p, x0.x, v0.x);
        v0.y = fmaf(p, x0.y, v0.y);
        v0.z = fmaf(p, x0.z, v0.z);
        v0.w = fmaf(p, x0.w, v0.w);
        v1.x = fmaf(p, x1.x, v1.x);
        v1.y = fmaf(p, x1.y, v1.y);
        v1.z = fmaf(p, x1.z, v1.z);
        v1.w = fmaf(p, x1.w, v1.w);
        if (seg == 0) { ps[row] = p; lsum += p; }
    }

    // stash v partials (16B-aligned: rg*132 + seg*8)
    {
        float* vr = vp + rg * 132 + seg * 8;
        ((float4*)vr)[0] = v0;
        ((float4*)vr)[1] = v1;
    }
    // block-reduce l (nonzero only on seg==0 lanes)
    float ls = lsum;
    #pragma unroll
    for (int off = 32; off > 0; off >>= 1) ls += __shfl_down(ls, off, 64);
    if (lane == 0) redl[wid] = ls;
    __syncthreads();   // vp + ps + redl visible

    float l = 0.f;
    #pragma unroll
    for (int w = 0; w < NW; ++w) l += redl[w];
    const float inv_l = 1.f / l;

    out_a[(size_t)b * Tn + tid] = ps[tid] * inv_l;

    if (tid < Dn) {
        float s = 0.f;
        #pragma unroll
        for (int r = 0; r < 32; ++r) s += vp[r * 132 + tid];
        out_v[(size_t)b * Dn + tid] = s * inv_l;
    }
}

extern "C" void kernel_launch(void* const* d_in, const int* in_sizes, int n_in,
                              void* d_out, int out_size, void* d_ws, size_t ws_size,
                              hipStream_t stream) {
    const float* input = (const float*)d_in[0];   // [B,T,D]
    const int*   mask  = (const int*)d_in[1];     // [B,T]
    const float* Wt    = (const float*)d_in[2];   // [D,H]
    const float* Wx    = (const float*)d_in[3];   // [D,H]
    const float* rate  = (const float*)d_in[4];   // [1]

    float* out   = (float*)d_out;
    float* out_v = out;                 // [B,D]  (return order: v, a)
    float* out_a = out + Bn * Dn;       // [B,T]

    single_attn_fused3<<<Bn, NT, 0, stream>>>(input, mask, Wt, Wx, rate, out_v, out_a);
}